// Round 1
// baseline (83.455 us; speedup 1.0000x reference)
//
#include <hip/hip_runtime.h>
#include <math.h>

#define BB 16
#define CI 64
#define CO 128
#define CX 69
#define LPIX 1024   // 32*32

// ---------------------------------------------------------------------------
// Kernel A: conv3x3 (zero-pad) + shape-distance + saf + q (1x1 conv reduce)
// grid: 256 blocks (16 batches x 16 row-stripes of 2 rows), 256 threads
// thread tile: 8 pixels x 4 out-channels
// ---------------------------------------------------------------------------
__launch_bounds__(256)
__global__ void convA(const float* __restrict__ xg,
                      const float* __restrict__ cwg,
                      const float* __restrict__ cbg,
                      const float* __restrict__ w2g,
                      const float* __restrict__ b2g,
                      const float* __restrict__ skg,
                      float* __restrict__ outg,
                      float* __restrict__ qg) {
  __shared__ float sk_t[45][CO];      // shapes_kernel transposed: [j][co]
  __shared__ float w_t[4][9][CO];     // conv weights chunk: [ci_local][tap][co]
  __shared__ float x_t[4][4][36];     // x chunk: [ci_local][row r0-1..r0+2][col pad]
  __shared__ float sw_t[5][9][64];    // shape windows: [c][tap][pixel]
  __shared__ float qred[4][64];

  const int tid = threadIdx.x;
  const int b  = blockIdx.x >> 4;
  const int r0 = (blockIdx.x & 15) * 2;

  const int pg  = tid & 7;        // pixel group (8 groups of 8 pixels)
  const int cg  = tid >> 3;       // channel group (32 groups of 4 channels)
  const int pr  = pg >> 2;        // row within stripe (0/1)
  const int pc0 = (pg & 3) * 8;   // first col of this thread's 8 pixels
  const int co0 = cg * 4;

  // stage shapes_kernel transposed (coalesced global read)
  for (int idx = tid; idx < 45 * CO; idx += 256) {
    int co = idx / 45, j = idx % 45;
    sk_t[j][co] = skg[idx];
  }
  // build shape windows (edge padding; channels 0,1 center-relative)
  const float* xs = xg + ((size_t)b * CX + CI) * LPIX;
  for (int idx = tid; idx < 5 * 9 * 64; idx += 256) {
    int c = idx / 576; int rem = idx % 576;
    int tap = rem / 64; int p = rem % 64;
    int prr = p >> 5, w = p & 31;
    int dr = tap / 3, dc = tap % 3;
    int hh = r0 + prr + dr - 1; hh = hh < 0 ? 0 : (hh > 31 ? 31 : hh);
    int wc = w + dc - 1;        wc = wc < 0 ? 0 : (wc > 31 ? 31 : wc);
    float v = xs[c * LPIX + hh * 32 + wc];
    if (c < 2) v -= xs[c * LPIX + (r0 + prr) * 32 + w];
    sw_t[c][tap][p] = v;
  }

  // accumulators initialized with conv bias
  float acc[8][4];
  {
    float4 bv = *(const float4*)&cbg[co0];
    #pragma unroll
    for (int p = 0; p < 8; ++p) {
      acc[p][0] = bv.x; acc[p][1] = bv.y; acc[p][2] = bv.z; acc[p][3] = bv.w;
    }
  }

  const float* xb = xg + (size_t)b * CX * LPIX;

  for (int ch = 0; ch < 16; ++ch) {
    const int ci0 = ch * 4;
    __syncthreads();
    // stage weight chunk: w_t[cil][tap][co] = cw[co][ci0+cil][tap]
    for (int idx = tid; idx < 4 * 9 * CO; idx += 256) {
      int co = idx / 36, rem = idx % 36;
      w_t[rem / 9][rem % 9][co] = cwg[co * 576 + ci0 * 9 + rem];
    }
    // stage x chunk (zero-pad), padded col: colp = w+1, rows r0-1..r0+2
    for (int idx = tid; idx < 4 * 4 * 36; idx += 256) {
      int cil = idx / 144; int rem = idx % 144;
      int rr = rem / 36; int colp = rem % 36;
      int hh = r0 - 1 + rr; int wc = colp - 1;
      float v = 0.f;
      if ((unsigned)hh < 32u && (unsigned)wc < 32u)
        v = xb[(ci0 + cil) * LPIX + hh * 32 + wc];
      x_t[cil][rr][colp] = v;
    }
    __syncthreads();
    #pragma unroll
    for (int cil = 0; cil < 4; ++cil) {
      float xr[3][12];
      #pragma unroll
      for (int dr = 0; dr < 3; ++dr) {
        #pragma unroll
        for (int q4 = 0; q4 < 3; ++q4)
          *(float4*)&xr[dr][q4 * 4] = *(const float4*)&x_t[cil][pr + dr][pc0 + q4 * 4];
      }
      #pragma unroll
      for (int dr = 0; dr < 3; ++dr) {
        #pragma unroll
        for (int dc = 0; dc < 3; ++dc) {
          float4 wv = *(const float4*)&w_t[cil][dr * 3 + dc][co0];
          #pragma unroll
          for (int p = 0; p < 8; ++p) {
            float xv = xr[dr][dc + p];
            acc[p][0] = fmaf(xv, wv.x, acc[p][0]);
            acc[p][1] = fmaf(xv, wv.y, acc[p][1]);
            acc[p][2] = fmaf(xv, wv.z, acc[p][2]);
            acc[p][3] = fmaf(xv, wv.w, acc[p][3]);
          }
        }
      }
    }
  }

  // shape distance: sd[p][i] = sum_j |sw[j][pixel] - sk[j][co]|
  float sd[8][4] = {{0.f}};
  const float* swbase = &sw_t[0][0][0] + pr * 32 + pc0;
  for (int j = 0; j < 45; ++j) {
    const float* swp = swbase + j * 64;
    float4 s0 = *(const float4*)swp;
    float4 s1 = *(const float4*)(swp + 4);
    float4 kv = *(const float4*)&sk_t[j][co0];
    float sw8[8] = {s0.x, s0.y, s0.z, s0.w, s1.x, s1.y, s1.z, s1.w};
    #pragma unroll
    for (int p = 0; p < 8; ++p) {
      sd[p][0] += fabsf(sw8[p] - kv.x);
      sd[p][1] += fabsf(sw8[p] - kv.y);
      sd[p][2] += fabsf(sw8[p] - kv.z);
      sd[p][3] += fabsf(sw8[p] - kv.w);
    }
  }

  // saf = relu(conv/(sd+1)); store; accumulate q partials
  float4 w2v = *(const float4*)&w2g[co0];
  const float b2 = b2g[0];
  float qp[8];
  #pragma unroll
  for (int p = 0; p < 8; ++p) qp[p] = 0.f;
  const int hrow = r0 + pr;
  float* outb = outg + (size_t)b * 133 * LPIX;
  #pragma unroll
  for (int i = 0; i < 4; ++i) {
    float w2i = (i == 0) ? w2v.x : (i == 1) ? w2v.y : (i == 2) ? w2v.z : w2v.w;
    float s[8];
    #pragma unroll
    for (int p = 0; p < 8; ++p) {
      float v = acc[p][i] / (sd[p][i] + 1.0f);
      v = v > 0.f ? v : 0.f;
      s[p] = v;
      qp[p] = fmaf(v, w2i, qp[p]);
    }
    float* o = outb + (size_t)(co0 + i) * LPIX + hrow * 32 + pc0;
    *(float4*)o       = make_float4(s[0], s[1], s[2], s[3]);
    *(float4*)(o + 4) = make_float4(s[4], s[5], s[6], s[7]);
  }
  // reduce q over the 32 channel groups: shfl within wave, LDS across waves
  #pragma unroll
  for (int m = 8; m <= 32; m <<= 1) {
    #pragma unroll
    for (int p = 0; p < 8; ++p) qp[p] += __shfl_xor(qp[p], m, 64);
  }
  if ((tid & 63) < 8) {
    #pragma unroll
    for (int p = 0; p < 8; ++p) qred[tid >> 6][(tid & 7) * 8 + p] = qp[p];
  }
  __syncthreads();
  if (tid < 64) {
    float qv = qred[0][tid] + qred[1][tid] + qred[2][tid] + qred[3][tid];
    qv = (qv + b2) * 0.08838834764831845f;  // 1/sqrt(128)
    qg[(size_t)b * LPIX + (r0 + (tid >> 5)) * 32 + (tid & 31)] = qv;
  }
}

// ---------------------------------------------------------------------------
// Kernel B: 3x3 zero-padded softmax of q + weighted window stats
// ---------------------------------------------------------------------------
__launch_bounds__(128)
__global__ void statsB(const float* __restrict__ xg,
                       const float* __restrict__ qg,
                       float* __restrict__ outg) {
  const int gid = blockIdx.x * 128 + threadIdx.x;  // 0..16383
  const int b = gid >> 10;
  const int h = (gid >> 5) & 31;
  const int w = gid & 31;

  const float* qb = qg + (size_t)b * LPIX;
  float qv[9];
  float m = -1e30f;
  #pragma unroll
  for (int t = 0; t < 9; ++t) {
    int hh = h + t / 3 - 1, wc = w + t % 3 - 1;
    float v = 0.f;  // zero padding participates in softmax
    if ((unsigned)hh < 32u && (unsigned)wc < 32u) v = qb[hh * 32 + wc];
    qv[t] = v;
    m = fmaxf(m, v);
  }
  float ssum = 0.f;
  #pragma unroll
  for (int t = 0; t < 9; ++t) { qv[t] = expf(qv[t] - m); ssum += qv[t]; }
  const float inv = 1.f / ssum;

  const float* xs = xg + ((size_t)b * CX + CI) * LPIX;
  float um0[9], um1[9];
  float m0 = 0.f, m1 = 0.f, v1a = 0.f, v1b = 0.f, c1 = 0.f;
  #pragma unroll
  for (int t = 0; t < 9; ++t) {
    int hh = h + t / 3 - 1; hh = hh < 0 ? 0 : (hh > 31 ? 31 : hh);  // edge pad
    int wc = w + t % 3 - 1; wc = wc < 0 ? 0 : (wc > 31 ? 31 : wc);
    int off = hh * 32 + wc;
    float quv = qv[t] * inv;
    qv[t] = quv;
    float a0 = xs[off];
    float a1 = xs[LPIX + off];
    float b0 = xs[2 * LPIX + off];
    float b1 = xs[3 * LPIX + off];
    float cc = xs[4 * LPIX + off];
    um0[t] = a0; um1[t] = a1;
    m0 = fmaf(a0, quv, m0);
    m1 = fmaf(a1, quv, m1);
    v1a = fmaf(b0, quv, v1a);
    v1b = fmaf(b1, quv, v1b);
    c1 = fmaf(cc, quv, c1);
  }
  float var0 = v1a, var1 = v1b, cov = c1;
  #pragma unroll
  for (int t = 0; t < 9; ++t) {
    float d0 = um0[t] - m0, d1 = um1[t] - m1;
    var0 = fmaf(d0 * d0, qv[t], var0);
    var1 = fmaf(d1 * d1, qv[t], var1);
    cov  = fmaf(d0 * d1, qv[t], cov);
  }
  float* ob = outg + ((size_t)b * 133 + 128) * LPIX + h * 32 + w;
  ob[0 * LPIX] = m0;
  ob[1 * LPIX] = m1;
  ob[2 * LPIX] = var0;
  ob[3 * LPIX] = var1;
  ob[4 * LPIX] = cov;
}

extern "C" void kernel_launch(void* const* d_in, const int* in_sizes, int n_in,
                              void* d_out, int out_size, void* d_ws, size_t ws_size,
                              hipStream_t stream) {
  const float* x  = (const float*)d_in[0];
  const float* cw = (const float*)d_in[1];
  const float* cb = (const float*)d_in[2];
  const float* w2 = (const float*)d_in[3];
  const float* b2 = (const float*)d_in[4];
  const float* sk = (const float*)d_in[5];
  float* out = (float*)d_out;
  float* q   = (float*)d_ws;  // 16*1024 floats = 64 KB scratch for q

  convA<<<dim3(256), dim3(256), 0, stream>>>(x, cw, cb, w2, b2, sk, out, q);
  statsB<<<dim3(128), dim3(128), 0, stream>>>(x, q, out);
}